// Round 8
// baseline (813.507 us; speedup 1.0000x reference)
//
#include <hip/hip_runtime.h>

#define NN 100000
#define NE 1600000
#define D1 128
#define D2 64
#define BN_EPS 1e-5f
#define SCAN_CHUNK 512
#define NB_SCAN ((NN + SCAN_CHUNK - 1) / SCAN_CHUNK)   // 196

typedef unsigned int uint32;
typedef unsigned short ushort;
typedef __attribute__((ext_vector_type(8))) short bf16x8;
typedef __attribute__((ext_vector_type(4))) float f32x4;

// ---- bf16 helpers (RNE) ----
__device__ __forceinline__ ushort f2bf1(float f) {
    uint32 u = __float_as_uint(f);
    return (ushort)((u + 0x7FFFu + ((u >> 16) & 1u)) >> 16);
}
__device__ __forceinline__ uint32 f2bf_pair(float a, float b) {
    uint32 ua = __float_as_uint(a), ub = __float_as_uint(b);
    ua = (ua + 0x7FFFu + ((ua >> 16) & 1u)) >> 16;
    ub = (ub + 0x7FFFu + ((ub >> 16) & 1u)) >> 16;
    return ua | (ub << 16);
}
__device__ __forceinline__ float bf_lo(uint32 v) { return __uint_as_float(v << 16); }
__device__ __forceinline__ float bf_hi(uint32 v) { return __uint_as_float(v & 0xFFFF0000u); }

// ---------------- degree count (int atomics, from dst) ----------------
__global__ __launch_bounds__(256) void cnt_k(const int* __restrict__ dst,
                                             int* __restrict__ cnt) {
    int i = blockIdx.x * 256 + threadIdx.x;
    if (i < NE) atomicAdd(&cnt[dst[i]], 1);
}

// ---------------- dis = rsqrt(cnt+1) ----------------
__global__ __launch_bounds__(256) void make_dis_k(const int* __restrict__ cnt,
                                                  float* __restrict__ dis) {
    int i = blockIdx.x * 256 + threadIdx.x;
    if (i < NN) dis[i] = rsqrtf((float)cnt[i] + 1.0f);
}

// ---------------- prefix scan (3 kernels) ----------------
__global__ __launch_bounds__(SCAN_CHUNK) void scan1_k(const int* __restrict__ cnt,
                                                      int* __restrict__ rowptr,
                                                      int* __restrict__ bsum) {
    __shared__ int sh[SCAN_CHUNK];
    int tid = threadIdx.x;
    int g = blockIdx.x * SCAN_CHUNK + tid;
    int v = (g < NN) ? cnt[g] : 0;
    sh[tid] = v;
    __syncthreads();
    for (int o = 1; o < SCAN_CHUNK; o <<= 1) {
        int t = (tid >= o) ? sh[tid - o] : 0;
        __syncthreads();
        sh[tid] += t;
        __syncthreads();
    }
    if (g < NN) rowptr[g] = sh[tid] - v;
    if (tid == SCAN_CHUNK - 1) bsum[blockIdx.x] = sh[tid];
}

__global__ void scan2_k(int* __restrict__ bsum) {
    if (threadIdx.x == 0 && blockIdx.x == 0) {
        int a = 0;
        for (int i = 0; i < NB_SCAN; ++i) { int t = bsum[i]; bsum[i] = a; a += t; }
    }
}

__global__ __launch_bounds__(256) void scan3_k(int* __restrict__ rowptr,
                                               const int* __restrict__ bsum) {
    int g = blockIdx.x * 256 + threadIdx.x;
    if (g < NN) rowptr[g] += bsum[g >> 9];
    if (g == 0) rowptr[NN] = NE;
}

// ---------------- CSR fill: slot-atomic per edge (src only; weight recomputed later) ----------------
__global__ __launch_bounds__(256) void fill_k(const int* __restrict__ src,
                                              const int* __restrict__ dst,
                                              const int* __restrict__ rowptr,
                                              int* __restrict__ cur,
                                              int* __restrict__ esrc) {
    int e = blockIdx.x * 256 + threadIdx.x;
    if (e >= NE) return;
    int d = dst[e];
    int s = src[e];
    int p = rowptr[d] + atomicAdd(&cur[d], 1);
    esrc[p] = s;
}

// ---------------- BN coefficients ----------------
__global__ void bncoef_k(const float* __restrict__ sums, const float* __restrict__ ssq,
                         const float* __restrict__ g, const float* __restrict__ beta,
                         float* __restrict__ coef, int dim) {
    int c = threadIdx.x;
    if (c >= dim) return;
    float m = sums[c] * (1.0f / NN);
    float var = ssq[c] * (1.0f / NN) - m * m;
    float sc = g[c] * rsqrtf(var + BN_EPS);
    coef[c] = sc;
    coef[dim + c] = beta[c] - m * sc;
}

// ---------------- W transpose + bf16 convert: Wt[c][k] = bf16(W[k][c]) ----------------
__global__ __launch_bounds__(256) void wt_k(const float* __restrict__ W1,
                                            const float* __restrict__ W2,
                                            ushort* __restrict__ wt1,
                                            ushort* __restrict__ wt2) {
    int i = blockIdx.x * 256 + threadIdx.x;
    if (i < 128 * 128) {
        int c = i >> 7, k = i & 127;
        wt1[i] = f2bf1(W1[k * 128 + c]);
    } else if (i < 128 * 128 + 64 * 128) {
        int o = i - 128 * 128;
        int c = o >> 7, k = o & 127;
        wt2[o] = f2bf1(W2[k * 64 + c]);
    }
}

// ---------------- MFMA GEMM: Yb[NN,OUT](bf16) = f(X)[NN,128] @ W[128,OUT] ----------------
template<int OUT, bool BF16BN>
__global__ __launch_bounds__(256) void mgemm_k(const void* __restrict__ Xv,
                                               const ushort* __restrict__ Wt,
                                               const float* __restrict__ coef,
                                               ushort* __restrict__ Yb) {
    const int lane = threadIdx.x & 63;
    const int wv = threadIdx.x >> 6;
    const int row0 = blockIdx.x * 64 + wv * 16;
    const int m = lane & 15;     // A row within strip / D col within tile
    const int kg = lane >> 4;    // k-group (0..3)
    const int rowA = min(row0 + m, NN - 1);
    f32x4 acc[OUT / 16];
    #pragma unroll
    for (int t = 0; t < OUT / 16; ++t) acc[t] = (f32x4){0.f, 0.f, 0.f, 0.f};

    #pragma unroll
    for (int kc = 0; kc < 128; kc += 32) {
        const int k0 = kc + kg * 8;
        float xs[8];
        if constexpr (BF16BN) {
            const ushort* Xb = (const ushort*)Xv;
            uint4 raw = *(const uint4*)(Xb + (size_t)rowA * 128 + k0);
            xs[0] = bf_lo(raw.x); xs[1] = bf_hi(raw.x);
            xs[2] = bf_lo(raw.y); xs[3] = bf_hi(raw.y);
            xs[4] = bf_lo(raw.z); xs[5] = bf_hi(raw.z);
            xs[6] = bf_lo(raw.w); xs[7] = bf_hi(raw.w);
            float4 sa = *(const float4*)(coef + k0);
            float4 sb = *(const float4*)(coef + k0 + 4);
            float4 ha = *(const float4*)(coef + 128 + k0);
            float4 hb = *(const float4*)(coef + 128 + k0 + 4);
            xs[0] = fmaxf(fmaf(xs[0], sa.x, ha.x), 0.f);
            xs[1] = fmaxf(fmaf(xs[1], sa.y, ha.y), 0.f);
            xs[2] = fmaxf(fmaf(xs[2], sa.z, ha.z), 0.f);
            xs[3] = fmaxf(fmaf(xs[3], sa.w, ha.w), 0.f);
            xs[4] = fmaxf(fmaf(xs[4], sb.x, hb.x), 0.f);
            xs[5] = fmaxf(fmaf(xs[5], sb.y, hb.y), 0.f);
            xs[6] = fmaxf(fmaf(xs[6], sb.z, hb.z), 0.f);
            xs[7] = fmaxf(fmaf(xs[7], sb.w, hb.w), 0.f);
        } else {
            const float* X = (const float*)Xv;
            float4 xa = *(const float4*)(X + (size_t)rowA * 128 + k0);
            float4 xb = *(const float4*)(X + (size_t)rowA * 128 + k0 + 4);
            xs[0] = xa.x; xs[1] = xa.y; xs[2] = xa.z; xs[3] = xa.w;
            xs[4] = xb.x; xs[5] = xb.y; xs[6] = xb.z; xs[7] = xb.w;
        }
        bf16x8 af;
        #pragma unroll
        for (int i = 0; i < 8; ++i) af[i] = (short)f2bf1(xs[i]);
        #pragma unroll
        for (int t = 0; t < OUT / 16; ++t) {
            bf16x8 bfr = *(const bf16x8*)(Wt + (size_t)(t * 16 + m) * 128 + k0);
            acc[t] = __builtin_amdgcn_mfma_f32_16x16x32_bf16(af, bfr, acc[t], 0, 0, 0);
        }
    }
    // D layout: col = lane&15 (=m), row = kg*4 + r
    #pragma unroll
    for (int t = 0; t < OUT / 16; ++t) {
        #pragma unroll
        for (int r = 0; r < 4; ++r) {
            int rr = row0 + kg * 4 + r;
            if (rr < NN) Yb[(size_t)rr * OUT + t * 16 + m] = f2bf1(acc[t][r]);
        }
    }
}

// ---------------- XCD-sliced CSR gather-aggregate + self-loop + bias + BN stats ----------------
// DIM=128: 8 slices of 16 cols (slice = bid&7 -> one slice per XCD, 3.2MB L2-resident).
// DIM=64:  4 slices of 16 cols (slice = bid&3; XCDs x and x+4 mirror, 3.2MB each).
// Wave = 8 edges x 8 lanes (1 bf16-pair per lane); per-node shfl reduce at the end.
template<int DIM>
__global__ __launch_bounds__(256) void aggs_k(const int* __restrict__ rowptr,
                                              const int* __restrict__ esrc,
                                              const float* __restrict__ dis,
                                              const uint32* __restrict__ xwb,
                                              const float* __restrict__ b,
                                              void* __restrict__ aggout,
                                              float* __restrict__ sums,
                                              float* __restrict__ ssq) {
    constexpr int SLICES = DIM / 16;            // 8 or 4
    constexpr int LOG2S = (DIM == 128) ? 3 : 2;
    constexpr int RU = DIM / 2;                 // row stride in u32
    const int slice = blockIdx.x & (SLICES - 1);
    const int lane = threadIdx.x & 63;
    const int g = lane >> 3;                    // edge sub-index 0..7
    const int c8 = lane & 7;                    // col-pair 0..7
    const int cp = slice * 8 + c8;              // u32 col within row
    const int wv = threadIdx.x >> 6;
    const int n0 = ((int)blockIdx.x >> LOG2S) * 4 + wv;
    const int nstride = ((int)gridDim.x >> LOG2S) * 4;
    float s0 = 0.f, s1 = 0.f, q0 = 0.f, q1 = 0.f;
    const float bc0 = b[cp * 2], bc1 = b[cp * 2 + 1];

    for (int n = n0; n < NN; n += nstride) {
        const int beg = rowptr[n], end = rowptr[n + 1];
        const float dn = dis[n];
        float ax = 0.f, ay = 0.f;
        int e = beg;
        for (; e + 16 <= end; e += 16) {
            int sa = __builtin_nontemporal_load(&esrc[e + g]);
            int sb = __builtin_nontemporal_load(&esrc[e + 8 + g]);
            float wa = dis[sa] * dn;
            float wb = dis[sb] * dn;
            uint32 va = xwb[(size_t)sa * RU + cp];
            uint32 vb = xwb[(size_t)sb * RU + cp];
            ax = fmaf(bf_lo(va), wa, ax); ay = fmaf(bf_hi(va), wa, ay);
            ax = fmaf(bf_lo(vb), wb, ax); ay = fmaf(bf_hi(vb), wb, ay);
        }
        for (; e < end; e += 8) {
            int ee = e + g;
            bool msk = ee < end;
            int s = msk ? __builtin_nontemporal_load(&esrc[ee]) : 0;
            float w = msk ? dis[s] * dn : 0.f;
            uint32 v = xwb[(size_t)s * RU + cp];
            ax = fmaf(bf_lo(v), w, ax);
            ay = fmaf(bf_hi(v), w, ay);
        }
        // reduce the 8 edge-groups: lanes {c8, c8+8, ..., c8+56} -> lane c8
        ax += __shfl_down(ax, 32); ay += __shfl_down(ay, 32);
        ax += __shfl_down(ax, 16); ay += __shfl_down(ay, 16);
        ax += __shfl_down(ax, 8);  ay += __shfl_down(ay, 8);
        if (lane < 8) {
            float sl = dn * dn;  // self-loop norm 1/(deg+1)
            uint32 xv = xwb[(size_t)n * RU + cp];
            ax = fmaf(bf_lo(xv), sl, ax) + bc0;
            ay = fmaf(bf_hi(xv), sl, ay) + bc1;
            if constexpr (DIM == 128)
                ((uint32*)aggout)[(size_t)n * RU + cp] = f2bf_pair(ax, ay);
            else
                ((float2*)aggout)[(size_t)n * 32 + cp] = make_float2(ax, ay);
            s0 += ax; q0 = fmaf(ax, ax, q0);
            s1 += ay; q1 = fmaf(ay, ay, q1);
        }
    }

    // block stats: this block touches only cols [slice*16, slice*16+16)
    __shared__ float ls[32];
    if (threadIdx.x < 32) ls[threadIdx.x] = 0.f;
    __syncthreads();
    if (lane < 8) {
        atomicAdd(&ls[c8 * 2], s0);
        atomicAdd(&ls[c8 * 2 + 1], s1);
        atomicAdd(&ls[16 + c8 * 2], q0);
        atomicAdd(&ls[16 + c8 * 2 + 1], q1);
    }
    __syncthreads();
    if (threadIdx.x < 16) atomicAdd(&sums[slice * 16 + threadIdx.x], ls[threadIdx.x]);
    else if (threadIdx.x < 32) atomicAdd(&ssq[slice * 16 + threadIdx.x - 16], ls[threadIdx.x]);
}

// ---------------- final: out = relu(BN2(h2)) @ Wf + bf ----------------
__global__ __launch_bounds__(256) void final_k(const float* __restrict__ h,
                                               const float* __restrict__ coef,
                                               const float* __restrict__ Wf,
                                               const float* __restrict__ bf,
                                               float* __restrict__ out) {
    int wid = (blockIdx.x * 256 + threadIdx.x) >> 6;
    int lane = threadIdx.x & 63;
    if (wid >= NN) return;
    float v = fmaxf(fmaf(h[(size_t)wid * 64 + lane], coef[lane], coef[64 + lane]), 0.f)
              * Wf[lane];
    #pragma unroll
    for (int o = 32; o > 0; o >>= 1) v += __shfl_down(v, o);
    if (lane == 0) out[wid] = v + bf[0];
}

extern "C" void kernel_launch(void* const* d_in, const int* in_sizes, int n_in,
                              void* d_out, int out_size, void* d_ws, size_t ws_size,
                              hipStream_t stream) {
    const float* x   = (const float*)d_in[0];
    const int*   ei  = (const int*)d_in[1];
    const int*   src = ei;
    const int*   dst = ei + NE;
    const float* W1  = (const float*)d_in[2];
    const float* b1  = (const float*)d_in[3];
    const float* g1  = (const float*)d_in[4];
    const float* be1 = (const float*)d_in[5];
    const float* W2  = (const float*)d_in[6];
    const float* b2  = (const float*)d_in[7];
    const float* g2  = (const float*)d_in[8];
    const float* be2 = (const float*)d_in[9];
    const float* Wf  = (const float*)d_in[10];
    const float* bf  = (const float*)d_in[11];
    float* out = (float*)d_out;

    // ---- workspace layout ----
    uint32* xwb   = (uint32*)d_ws;                     // NN*64 u32 (bf16 xw, both layers)
    uint32* agg1b = xwb + (size_t)NN * 64;             // NN*64 u32 (bf16 h1 pre-BN)
    float*  agg2  = (float*)(agg1b + (size_t)NN * 64); // NN*64 f32
    float*  dis   = agg2 + (size_t)NN * D2;            // NN
    float*  sums1 = dis + NN;                          // 128
    float*  ssq1  = sums1 + D1;
    float*  sums2 = ssq1 + D1;
    float*  ssq2  = sums2 + D2;
    float*  coef1 = ssq2 + D2;                         // 256
    float*  coef2 = coef1 + 2 * D1;                    // 128
    ushort* wt1   = (ushort*)(coef2 + 2 * D2);         // 128*128 bf16
    ushort* wt2   = wt1 + 128 * 128;                   // 64*128 bf16
    int*    cnt    = (int*)(wt2 + 64 * 128);           // NN
    int*    cur    = cnt + NN;                         // NN
    int*    rowptr = cur + NN;                         // NN+1
    int*    bsum   = rowptr + NN + 1;                  // 256
    int*    esrc   = bsum + 256;                       // NE

    hipMemsetAsync(cnt, 0, sizeof(int) * 2 * NN, stream);
    hipMemsetAsync(sums1, 0, sizeof(float) * (2 * D1 + 2 * D2), stream);

    // ---- CSR build + weight prep ----
    cnt_k<<<(NE + 255) / 256, 256, 0, stream>>>(dst, cnt);
    make_dis_k<<<(NN + 255) / 256, 256, 0, stream>>>(cnt, dis);
    scan1_k<<<NB_SCAN, SCAN_CHUNK, 0, stream>>>(cnt, rowptr, bsum);
    scan2_k<<<1, 64, 0, stream>>>(bsum);
    scan3_k<<<(NN + 255) / 256, 256, 0, stream>>>(rowptr, bsum);
    fill_k<<<(NE + 255) / 256, 256, 0, stream>>>(src, dst, rowptr, cur, esrc);
    wt_k<<<(128 * 128 + 64 * 128 + 255) / 256, 256, 0, stream>>>(W1, W2, wt1, wt2);

    // ---- layer 1 ----
    mgemm_k<128, false><<<(NN + 63) / 64, 256, 0, stream>>>(x, wt1, nullptr, (ushort*)xwb);
    aggs_k<128><<<2048, 256, 0, stream>>>(rowptr, esrc, dis, xwb, b1, agg1b, sums1, ssq1);
    bncoef_k<<<1, 128, 0, stream>>>(sums1, ssq1, g1, be1, coef1, D1);

    // ---- layer 2 (BN1+ReLU fused into GEMM input load, bf16 input) ----
    mgemm_k<64, true><<<(NN + 63) / 64, 256, 0, stream>>>(agg1b, wt2, coef1, (ushort*)xwb);
    aggs_k<64><<<2048, 256, 0, stream>>>(rowptr, esrc, dis, xwb, b2, agg2, sums2, ssq2);
    bncoef_k<<<1, 64, 0, stream>>>(sums2, ssq2, g2, be2, coef2, D2);

    // ---- final projection (BN2+ReLU fused) ----
    final_k<<<(NN * 64 + 255) / 256, 256, 0, stream>>>(agg2, coef2, Wf, bf, out);
}

// Round 9
// 496.527 us; speedup vs baseline: 1.6384x; 1.6384x over previous
//
#include <hip/hip_runtime.h>

#define NN 100000
#define NE 1600000
#define D1 128
#define D2 64
#define BN_EPS 1e-5f
#define SCAN_CHUNK 512
#define NB_SCAN ((NN + SCAN_CHUNK - 1) / SCAN_CHUNK)   // 196

typedef unsigned int uint32;
typedef unsigned short ushort;
typedef __attribute__((ext_vector_type(8))) short bf16x8;
typedef __attribute__((ext_vector_type(4))) float f32x4;

// ---- bf16 helpers (RNE) ----
__device__ __forceinline__ ushort f2bf1(float f) {
    uint32 u = __float_as_uint(f);
    return (ushort)((u + 0x7FFFu + ((u >> 16) & 1u)) >> 16);
}
__device__ __forceinline__ uint32 f2bf_pair(float a, float b) {
    uint32 ua = __float_as_uint(a), ub = __float_as_uint(b);
    ua = (ua + 0x7FFFu + ((ua >> 16) & 1u)) >> 16;
    ub = (ub + 0x7FFFu + ((ub >> 16) & 1u)) >> 16;
    return ua | (ub << 16);
}
__device__ __forceinline__ float bf_lo(uint32 v) { return __uint_as_float(v << 16); }
__device__ __forceinline__ float bf_hi(uint32 v) { return __uint_as_float(v & 0xFFFF0000u); }

// ---------------- degree count (int atomics, from dst) ----------------
__global__ __launch_bounds__(256) void cnt_k(const int* __restrict__ dst,
                                             int* __restrict__ cnt) {
    int i = blockIdx.x * 256 + threadIdx.x;
    if (i < NE) atomicAdd(&cnt[dst[i]], 1);
}

// ---------------- dis = rsqrt(cnt+1) ----------------
__global__ __launch_bounds__(256) void make_dis_k(const int* __restrict__ cnt,
                                                  float* __restrict__ dis) {
    int i = blockIdx.x * 256 + threadIdx.x;
    if (i < NN) dis[i] = rsqrtf((float)cnt[i] + 1.0f);
}

// ---------------- prefix scan (3 kernels) ----------------
__global__ __launch_bounds__(SCAN_CHUNK) void scan1_k(const int* __restrict__ cnt,
                                                      int* __restrict__ rowptr,
                                                      int* __restrict__ bsum) {
    __shared__ int sh[SCAN_CHUNK];
    int tid = threadIdx.x;
    int g = blockIdx.x * SCAN_CHUNK + tid;
    int v = (g < NN) ? cnt[g] : 0;
    sh[tid] = v;
    __syncthreads();
    for (int o = 1; o < SCAN_CHUNK; o <<= 1) {
        int t = (tid >= o) ? sh[tid - o] : 0;
        __syncthreads();
        sh[tid] += t;
        __syncthreads();
    }
    if (g < NN) rowptr[g] = sh[tid] - v;
    if (tid == SCAN_CHUNK - 1) bsum[blockIdx.x] = sh[tid];
}

__global__ void scan2_k(int* __restrict__ bsum) {
    if (threadIdx.x == 0 && blockIdx.x == 0) {
        int a = 0;
        for (int i = 0; i < NB_SCAN; ++i) { int t = bsum[i]; bsum[i] = a; a += t; }
    }
}

__global__ __launch_bounds__(256) void scan3_k(int* __restrict__ rowptr,
                                               const int* __restrict__ bsum) {
    int g = blockIdx.x * 256 + threadIdx.x;
    if (g < NN) rowptr[g] += bsum[g >> 9];
    if (g == 0) rowptr[NN] = NE;
}

// ---------------- CSR fill: slot-atomic per edge (separate src / weight streams) ----------------
__global__ __launch_bounds__(256) void fill_k(const int* __restrict__ src,
                                              const int* __restrict__ dst,
                                              const int* __restrict__ rowptr,
                                              const float* __restrict__ dis,
                                              int* __restrict__ cur,
                                              int* __restrict__ esrc,
                                              float* __restrict__ ew) {
    int e = blockIdx.x * 256 + threadIdx.x;
    if (e >= NE) return;
    int d = dst[e];
    int s = src[e];
    int p = rowptr[d] + atomicAdd(&cur[d], 1);
    esrc[p] = s;
    ew[p] = dis[s] * dis[d];
}

// ---------------- BN coefficients ----------------
__global__ void bncoef_k(const float* __restrict__ sums, const float* __restrict__ ssq,
                         const float* __restrict__ g, const float* __restrict__ beta,
                         float* __restrict__ coef, int dim) {
    int c = threadIdx.x;
    if (c >= dim) return;
    float m = sums[c] * (1.0f / NN);
    float var = ssq[c] * (1.0f / NN) - m * m;
    float sc = g[c] * rsqrtf(var + BN_EPS);
    coef[c] = sc;
    coef[dim + c] = beta[c] - m * sc;
}

// ---------------- W transpose + bf16 convert: Wt[c][k] = bf16(W[k][c]) ----------------
__global__ __launch_bounds__(256) void wt_k(const float* __restrict__ W1,
                                            const float* __restrict__ W2,
                                            ushort* __restrict__ wt1,
                                            ushort* __restrict__ wt2) {
    int i = blockIdx.x * 256 + threadIdx.x;
    if (i < 128 * 128) {
        int c = i >> 7, k = i & 127;
        wt1[i] = f2bf1(W1[k * 128 + c]);
    } else if (i < 128 * 128 + 64 * 128) {
        int o = i - 128 * 128;
        int c = o >> 7, k = o & 127;
        wt2[o] = f2bf1(W2[k * 64 + c]);
    }
}

// ---------------- MFMA GEMM: Yb[NN,OUT](bf16) = f(X)[NN,128] @ W[128,OUT] ----------------
template<int OUT, bool BF16BN>
__global__ __launch_bounds__(256) void mgemm_k(const void* __restrict__ Xv,
                                               const ushort* __restrict__ Wt,
                                               const float* __restrict__ coef,
                                               ushort* __restrict__ Yb) {
    const int lane = threadIdx.x & 63;
    const int wv = threadIdx.x >> 6;
    const int row0 = blockIdx.x * 64 + wv * 16;
    const int m = lane & 15;     // A row within strip / D col within tile
    const int kg = lane >> 4;    // k-group (0..3)
    const int rowA = min(row0 + m, NN - 1);
    f32x4 acc[OUT / 16];
    #pragma unroll
    for (int t = 0; t < OUT / 16; ++t) acc[t] = (f32x4){0.f, 0.f, 0.f, 0.f};

    #pragma unroll
    for (int kc = 0; kc < 128; kc += 32) {
        const int k0 = kc + kg * 8;
        float xs[8];
        if constexpr (BF16BN) {
            const ushort* Xb = (const ushort*)Xv;
            uint4 raw = *(const uint4*)(Xb + (size_t)rowA * 128 + k0);
            xs[0] = bf_lo(raw.x); xs[1] = bf_hi(raw.x);
            xs[2] = bf_lo(raw.y); xs[3] = bf_hi(raw.y);
            xs[4] = bf_lo(raw.z); xs[5] = bf_hi(raw.z);
            xs[6] = bf_lo(raw.w); xs[7] = bf_hi(raw.w);
            float4 sa = *(const float4*)(coef + k0);
            float4 sb = *(const float4*)(coef + k0 + 4);
            float4 ha = *(const float4*)(coef + 128 + k0);
            float4 hb = *(const float4*)(coef + 128 + k0 + 4);
            xs[0] = fmaxf(fmaf(xs[0], sa.x, ha.x), 0.f);
            xs[1] = fmaxf(fmaf(xs[1], sa.y, ha.y), 0.f);
            xs[2] = fmaxf(fmaf(xs[2], sa.z, ha.z), 0.f);
            xs[3] = fmaxf(fmaf(xs[3], sa.w, ha.w), 0.f);
            xs[4] = fmaxf(fmaf(xs[4], sb.x, hb.x), 0.f);
            xs[5] = fmaxf(fmaf(xs[5], sb.y, hb.y), 0.f);
            xs[6] = fmaxf(fmaf(xs[6], sb.z, hb.z), 0.f);
            xs[7] = fmaxf(fmaf(xs[7], sb.w, hb.w), 0.f);
        } else {
            const float* X = (const float*)Xv;
            float4 xa = *(const float4*)(X + (size_t)rowA * 128 + k0);
            float4 xb = *(const float4*)(X + (size_t)rowA * 128 + k0 + 4);
            xs[0] = xa.x; xs[1] = xa.y; xs[2] = xa.z; xs[3] = xa.w;
            xs[4] = xb.x; xs[5] = xb.y; xs[6] = xb.z; xs[7] = xb.w;
        }
        bf16x8 af;
        #pragma unroll
        for (int i = 0; i < 8; ++i) af[i] = (short)f2bf1(xs[i]);
        #pragma unroll
        for (int t = 0; t < OUT / 16; ++t) {
            bf16x8 bfr = *(const bf16x8*)(Wt + (size_t)(t * 16 + m) * 128 + k0);
            acc[t] = __builtin_amdgcn_mfma_f32_16x16x32_bf16(af, bfr, acc[t], 0, 0, 0);
        }
    }
    // D layout: col = lane&15 (=m), row = kg*4 + r
    #pragma unroll
    for (int t = 0; t < OUT / 16; ++t) {
        #pragma unroll
        for (int r = 0; r < 4; ++r) {
            int rr = row0 + kg * 4 + r;
            if (rr < NN) Yb[(size_t)rr * OUT + t * 16 + m] = f2bf1(acc[t][r]);
        }
    }
}

// ---------------- agg layer1 (D=128): one wave/node, 16-deep gather pipeline, bf16 in/out ----------------
__global__ __launch_bounds__(256) void agg128_k(const int* __restrict__ rowptr,
                                                const int* __restrict__ esrc,
                                                const float* __restrict__ ew,
                                                const float* __restrict__ dis,
                                                const uint32* __restrict__ xwb,
                                                const float* __restrict__ b,
                                                uint32* __restrict__ agg1b,
                                                float* __restrict__ sums,
                                                float* __restrict__ ssq) {
    const int lane = threadIdx.x & 63;
    const int wid = (blockIdx.x * 256 + threadIdx.x) >> 6;
    const int nwaves = gridDim.x * 4;
    float s0 = 0.f, s1 = 0.f, q0 = 0.f, q1 = 0.f;
    const float bc0 = b[lane * 2], bc1 = b[lane * 2 + 1];

    for (int n = wid; n < NN; n += nwaves) {
        const int beg = rowptr[n], end = rowptr[n + 1];
        const float dn = dis[n];
        float ax = 0.f, ay = 0.f;
        int e = beg;
        for (; e + 16 <= end; e += 16) {
            int idx[16]; float w[16]; uint32 vv[16];
            #pragma unroll
            for (int j = 0; j < 16; ++j) idx[j] = esrc[e + j];
            #pragma unroll
            for (int j = 0; j < 16; ++j) w[j] = ew[e + j];
            #pragma unroll
            for (int j = 0; j < 16; ++j)
                vv[j] = xwb[(size_t)idx[j] * 64 + lane];
            #pragma unroll
            for (int j = 0; j < 16; ++j) {
                ax = fmaf(bf_lo(vv[j]), w[j], ax);
                ay = fmaf(bf_hi(vv[j]), w[j], ay);
            }
        }
        for (; e + 8 <= end; e += 8) {
            int idx[8]; float w[8]; uint32 vv[8];
            #pragma unroll
            for (int j = 0; j < 8; ++j) idx[j] = esrc[e + j];
            #pragma unroll
            for (int j = 0; j < 8; ++j) w[j] = ew[e + j];
            #pragma unroll
            for (int j = 0; j < 8; ++j)
                vv[j] = xwb[(size_t)idx[j] * 64 + lane];
            #pragma unroll
            for (int j = 0; j < 8; ++j) {
                ax = fmaf(bf_lo(vv[j]), w[j], ax);
                ay = fmaf(bf_hi(vv[j]), w[j], ay);
            }
        }
        for (; e < end; ++e) {
            int s = esrc[e];
            float w = ew[e];
            uint32 v = xwb[(size_t)s * 64 + lane];
            ax = fmaf(bf_lo(v), w, ax);
            ay = fmaf(bf_hi(v), w, ay);
        }
        float sl = dn * dn;  // self-loop norm 1/(deg+1)
        uint32 xv = xwb[(size_t)n * 64 + lane];
        ax = fmaf(bf_lo(xv), sl, ax) + bc0;
        ay = fmaf(bf_hi(xv), sl, ay) + bc1;
        agg1b[(size_t)n * 64 + lane] = f2bf_pair(ax, ay);
        s0 += ax; q0 = fmaf(ax, ax, q0);
        s1 += ay; q1 = fmaf(ay, ay, q1);
    }

    __shared__ float ls[256];
    ls[threadIdx.x] = 0.f;  // 256 = 2*D1
    __syncthreads();
    atomicAdd(&ls[lane * 2], s0);
    atomicAdd(&ls[lane * 2 + 1], s1);
    atomicAdd(&ls[128 + lane * 2], q0);
    atomicAdd(&ls[128 + lane * 2 + 1], q1);
    __syncthreads();
    if (threadIdx.x < 128) atomicAdd(&sums[threadIdx.x], ls[threadIdx.x]);
    else atomicAdd(&ssq[threadIdx.x - 128], ls[threadIdx.x]);
}

// ---------------- agg layer2 (D=64): half-wave per edge, 16 per half in flight ----------------
__global__ __launch_bounds__(256) void agg64_k(const int* __restrict__ rowptr,
                                               const int* __restrict__ esrc,
                                               const float* __restrict__ ew,
                                               const float* __restrict__ dis,
                                               const uint32* __restrict__ xwb,  // 32 uint32/row
                                               const float* __restrict__ b,
                                               float* __restrict__ agg,
                                               float* __restrict__ sums,
                                               float* __restrict__ ssq) {
    const int lane = threadIdx.x & 63;
    const int half = lane >> 5;       // 0 or 1
    const int sl = lane & 31;         // covers cols {2sl, 2sl+1}
    const int wid = (blockIdx.x * 256 + threadIdx.x) >> 6;
    const int nwaves = gridDim.x * 4;
    float s0 = 0.f, s1 = 0.f, q0 = 0.f, q1 = 0.f;
    const float bc0 = b[sl * 2], bc1 = b[sl * 2 + 1];

    for (int n = wid; n < NN; n += nwaves) {
        const int beg = rowptr[n], end = rowptr[n + 1];
        const float dn = dis[n];
        float ax = 0.f, ay = 0.f;
        int e = beg;
        for (; e + 32 <= end; e += 32) {
            int idx[16]; float w[16]; uint32 vv[16];
            #pragma unroll
            for (int j = 0; j < 16; ++j) idx[j] = esrc[e + 2 * j + half];
            #pragma unroll
            for (int j = 0; j < 16; ++j) w[j] = ew[e + 2 * j + half];
            #pragma unroll
            for (int j = 0; j < 16; ++j)
                vv[j] = xwb[(size_t)idx[j] * 32 + sl];
            #pragma unroll
            for (int j = 0; j < 16; ++j) {
                ax = fmaf(bf_lo(vv[j]), w[j], ax);
                ay = fmaf(bf_hi(vv[j]), w[j], ay);
            }
        }
        for (; e + 16 <= end; e += 16) {
            int idx[8]; float w[8]; uint32 vv[8];
            #pragma unroll
            for (int j = 0; j < 8; ++j) idx[j] = esrc[e + 2 * j + half];
            #pragma unroll
            for (int j = 0; j < 8; ++j) w[j] = ew[e + 2 * j + half];
            #pragma unroll
            for (int j = 0; j < 8; ++j)
                vv[j] = xwb[(size_t)idx[j] * 32 + sl];
            #pragma unroll
            for (int j = 0; j < 8; ++j) {
                ax = fmaf(bf_lo(vv[j]), w[j], ax);
                ay = fmaf(bf_hi(vv[j]), w[j], ay);
            }
        }
        for (; e + 2 <= end; e += 2) {
            int s = esrc[e + half];
            float w = ew[e + half];
            uint32 v = xwb[(size_t)s * 32 + sl];
            ax = fmaf(bf_lo(v), w, ax);
            ay = fmaf(bf_hi(v), w, ay);
        }
        if (e < end && half == 0) {
            int s = esrc[e];
            float w = ew[e];
            uint32 v = xwb[(size_t)s * 32 + sl];
            ax = fmaf(bf_lo(v), w, ax);
            ay = fmaf(bf_hi(v), w, ay);
        }
        ax += __shfl_down(ax, 32);
        ay += __shfl_down(ay, 32);
        if (half == 0) {
            float slf = dn * dn;
            uint32 xv = xwb[(size_t)n * 32 + sl];
            ax = fmaf(bf_lo(xv), slf, ax) + bc0;
            ay = fmaf(bf_hi(xv), slf, ay) + bc1;
            *(float2*)&agg[(size_t)n * 64 + sl * 2] = make_float2(ax, ay);
            s0 += ax; q0 = fmaf(ax, ax, q0);
            s1 += ay; q1 = fmaf(ay, ay, q1);
        }
    }

    __shared__ float ls[128];  // 2*D2
    if (threadIdx.x < 128) ls[threadIdx.x] = 0.f;
    __syncthreads();
    if (half == 0) {
        atomicAdd(&ls[sl * 2], s0);
        atomicAdd(&ls[sl * 2 + 1], s1);
        atomicAdd(&ls[64 + sl * 2], q0);
        atomicAdd(&ls[64 + sl * 2 + 1], q1);
    }
    __syncthreads();
    if (threadIdx.x < 64) atomicAdd(&sums[threadIdx.x], ls[threadIdx.x]);
    else if (threadIdx.x < 128) atomicAdd(&ssq[threadIdx.x - 64], ls[threadIdx.x]);
}

// ---------------- final: out = relu(BN2(h2)) @ Wf + bf ----------------
__global__ __launch_bounds__(256) void final_k(const float* __restrict__ h,
                                               const float* __restrict__ coef,
                                               const float* __restrict__ Wf,
                                               const float* __restrict__ bf,
                                               float* __restrict__ out) {
    int wid = (blockIdx.x * 256 + threadIdx.x) >> 6;
    int lane = threadIdx.x & 63;
    if (wid >= NN) return;
    float v = fmaxf(fmaf(h[(size_t)wid * 64 + lane], coef[lane], coef[64 + lane]), 0.f)
              * Wf[lane];
    #pragma unroll
    for (int o = 32; o > 0; o >>= 1) v += __shfl_down(v, o);
    if (lane == 0) out[wid] = v + bf[0];
}

extern "C" void kernel_launch(void* const* d_in, const int* in_sizes, int n_in,
                              void* d_out, int out_size, void* d_ws, size_t ws_size,
                              hipStream_t stream) {
    const float* x   = (const float*)d_in[0];
    const int*   ei  = (const int*)d_in[1];
    const int*   src = ei;
    const int*   dst = ei + NE;
    const float* W1  = (const float*)d_in[2];
    const float* b1  = (const float*)d_in[3];
    const float* g1  = (const float*)d_in[4];
    const float* be1 = (const float*)d_in[5];
    const float* W2  = (const float*)d_in[6];
    const float* b2  = (const float*)d_in[7];
    const float* g2  = (const float*)d_in[8];
    const float* be2 = (const float*)d_in[9];
    const float* Wf  = (const float*)d_in[10];
    const float* bf  = (const float*)d_in[11];
    float* out = (float*)d_out;

    // ---- workspace layout ----
    uint32* xwb   = (uint32*)d_ws;                     // NN*64 u32 (bf16 xw, both layers)
    uint32* agg1b = xwb + (size_t)NN * 64;             // NN*64 u32 (bf16 h1 pre-BN)
    float*  agg2  = (float*)(agg1b + (size_t)NN * 64); // NN*64 f32
    float*  dis   = agg2 + (size_t)NN * D2;            // NN
    float*  sums1 = dis + NN;                          // 128
    float*  ssq1  = sums1 + D1;
    float*  sums2 = ssq1 + D1;
    float*  ssq2  = sums2 + D2;
    float*  coef1 = ssq2 + D2;                         // 256
    float*  coef2 = coef1 + 2 * D1;                    // 128
    ushort* wt1   = (ushort*)(coef2 + 2 * D2);         // 128*128 bf16
    ushort* wt2   = wt1 + 128 * 128;                   // 64*128 bf16
    int*    cnt    = (int*)(wt2 + 64 * 128);           // NN
    int*    cur    = cnt + NN;                         // NN
    int*    rowptr = cur + NN;                         // NN+1
    int*    bsum   = rowptr + NN + 1;                  // 256
    int*    esrc   = bsum + 256;                       // NE
    float*  ew     = (float*)(esrc + NE);              // NE

    hipMemsetAsync(cnt, 0, sizeof(int) * 2 * NN, stream);
    hipMemsetAsync(sums1, 0, sizeof(float) * (2 * D1 + 2 * D2), stream);

    // ---- CSR build + weight prep ----
    cnt_k<<<(NE + 255) / 256, 256, 0, stream>>>(dst, cnt);
    make_dis_k<<<(NN + 255) / 256, 256, 0, stream>>>(cnt, dis);
    scan1_k<<<NB_SCAN, SCAN_CHUNK, 0, stream>>>(cnt, rowptr, bsum);
    scan2_k<<<1, 64, 0, stream>>>(bsum);
    scan3_k<<<(NN + 255) / 256, 256, 0, stream>>>(rowptr, bsum);
    fill_k<<<(NE + 255) / 256, 256, 0, stream>>>(src, dst, rowptr, dis, cur, esrc, ew);
    wt_k<<<(128 * 128 + 64 * 128 + 255) / 256, 256, 0, stream>>>(W1, W2, wt1, wt2);

    // ---- layer 1 ----
    mgemm_k<128, false><<<(NN + 63) / 64, 256, 0, stream>>>(x, wt1, nullptr, (ushort*)xwb);
    agg128_k<<<2048, 256, 0, stream>>>(rowptr, esrc, ew, dis, xwb, b1, agg1b, sums1, ssq1);
    bncoef_k<<<1, 128, 0, stream>>>(sums1, ssq1, g1, be1, coef1, D1);

    // ---- layer 2 (BN1+ReLU fused into GEMM input load, bf16 input) ----
    mgemm_k<64, true><<<(NN + 63) / 64, 256, 0, stream>>>(agg1b, wt2, coef1, (ushort*)xwb);
    agg64_k<<<2048, 256, 0, stream>>>(rowptr, esrc, ew, dis, xwb, b2, agg2, sums2, ssq2);
    bncoef_k<<<1, 64, 0, stream>>>(sums2, ssq2, g2, be2, coef2, D2);

    // ---- final projection (BN2+ReLU fused) ----
    final_k<<<(NN * 64 + 255) / 256, 256, 0, stream>>>(agg2, coef2, Wf, bf, out);
}

// Round 10
// 472.712 us; speedup vs baseline: 1.7209x; 1.0504x over previous
//
#include <hip/hip_runtime.h>

#define NN 100000
#define NE 1600000
#define D1 128
#define D2 64
#define BN_EPS 1e-5f
#define SCAN_CHUNK 512
#define NB_SCAN ((NN + SCAN_CHUNK - 1) / SCAN_CHUNK)   // 196

typedef unsigned int uint32;
typedef unsigned short ushort;
typedef __attribute__((ext_vector_type(8))) short bf16x8;
typedef __attribute__((ext_vector_type(4))) float f32x4;

// ---- bf16 helpers (RNE) ----
__device__ __forceinline__ ushort f2bf1(float f) {
    uint32 u = __float_as_uint(f);
    return (ushort)((u + 0x7FFFu + ((u >> 16) & 1u)) >> 16);
}
__device__ __forceinline__ uint32 f2bf_pair(float a, float b) {
    uint32 ua = __float_as_uint(a), ub = __float_as_uint(b);
    ua = (ua + 0x7FFFu + ((ua >> 16) & 1u)) >> 16;
    ub = (ub + 0x7FFFu + ((ub >> 16) & 1u)) >> 16;
    return ua | (ub << 16);
}
__device__ __forceinline__ float bf_lo(uint32 v) { return __uint_as_float(v << 16); }
__device__ __forceinline__ float bf_hi(uint32 v) { return __uint_as_float(v & 0xFFFF0000u); }

// ---------------- degree count (int atomics, from dst) ----------------
__global__ __launch_bounds__(256) void cnt_k(const int* __restrict__ dst,
                                             int* __restrict__ cnt) {
    int i = blockIdx.x * 256 + threadIdx.x;
    if (i < NE) atomicAdd(&cnt[dst[i]], 1);
}

// ---------------- prefix scan (3 kernels); scan1 also emits dis = rsqrt(cnt+1) ----------------
__global__ __launch_bounds__(SCAN_CHUNK) void scan1_k(const int* __restrict__ cnt,
                                                      int* __restrict__ rowptr,
                                                      int* __restrict__ bsum,
                                                      float* __restrict__ dis) {
    __shared__ int sh[SCAN_CHUNK];
    int tid = threadIdx.x;
    int g = blockIdx.x * SCAN_CHUNK + tid;
    int v = (g < NN) ? cnt[g] : 0;
    if (g < NN) dis[g] = rsqrtf((float)v + 1.0f);
    sh[tid] = v;
    __syncthreads();
    for (int o = 1; o < SCAN_CHUNK; o <<= 1) {
        int t = (tid >= o) ? sh[tid - o] : 0;
        __syncthreads();
        sh[tid] += t;
        __syncthreads();
    }
    if (g < NN) rowptr[g] = sh[tid] - v;
    if (tid == SCAN_CHUNK - 1) bsum[blockIdx.x] = sh[tid];
}

__global__ void scan2_k(int* __restrict__ bsum) {
    if (threadIdx.x == 0 && blockIdx.x == 0) {
        int a = 0;
        for (int i = 0; i < NB_SCAN; ++i) { int t = bsum[i]; bsum[i] = a; a += t; }
    }
}

__global__ __launch_bounds__(256) void scan3_k(int* __restrict__ rowptr,
                                               const int* __restrict__ bsum) {
    int g = blockIdx.x * 256 + threadIdx.x;
    if (g < NN) rowptr[g] += bsum[g >> 9];
    if (g == 0) rowptr[NN] = NE;
}

// ---------------- CSR fill: slot-atomic per edge (separate src / weight streams) ----------------
__global__ __launch_bounds__(256) void fill_k(const int* __restrict__ src,
                                              const int* __restrict__ dst,
                                              const int* __restrict__ rowptr,
                                              const float* __restrict__ dis,
                                              int* __restrict__ cur,
                                              int* __restrict__ esrc,
                                              float* __restrict__ ew) {
    int e = blockIdx.x * 256 + threadIdx.x;
    if (e >= NE) return;
    int d = dst[e];
    int s = src[e];
    int p = rowptr[d] + atomicAdd(&cur[d], 1);
    esrc[p] = s;
    ew[p] = dis[s] * dis[d];
}

// ---------------- W transpose + bf16 convert: Wt[c][k] = bf16(W[k][c]) ----------------
__global__ __launch_bounds__(256) void wt_k(const float* __restrict__ W1,
                                            const float* __restrict__ W2,
                                            ushort* __restrict__ wt1,
                                            ushort* __restrict__ wt2) {
    int i = blockIdx.x * 256 + threadIdx.x;
    if (i < 128 * 128) {
        int c = i >> 7, k = i & 127;
        wt1[i] = f2bf1(W1[k * 128 + c]);
    } else if (i < 128 * 128 + 64 * 128) {
        int o = i - 128 * 128;
        int c = o >> 7, k = o & 127;
        wt2[o] = f2bf1(W2[k * 64 + c]);
    }
}

// ---------------- MFMA GEMM layer1: xwb[NN,128](bf16) = x[NN,128]f32 @ W1 ----------------
__global__ __launch_bounds__(256) void mgemm1_k(const float* __restrict__ X,
                                                const ushort* __restrict__ Wt,
                                                ushort* __restrict__ Yb) {
    const int lane = threadIdx.x & 63;
    const int wv = threadIdx.x >> 6;
    const int row0 = blockIdx.x * 64 + wv * 16;
    const int m = lane & 15;
    const int kg = lane >> 4;
    const int rowA = min(row0 + m, NN - 1);
    f32x4 acc[8];
    #pragma unroll
    for (int t = 0; t < 8; ++t) acc[t] = (f32x4){0.f, 0.f, 0.f, 0.f};

    #pragma unroll
    for (int kc = 0; kc < 128; kc += 32) {
        const int k0 = kc + kg * 8;
        float4 xa = *(const float4*)(X + (size_t)rowA * 128 + k0);
        float4 xb = *(const float4*)(X + (size_t)rowA * 128 + k0 + 4);
        bf16x8 af;
        af[0] = (short)f2bf1(xa.x); af[1] = (short)f2bf1(xa.y);
        af[2] = (short)f2bf1(xa.z); af[3] = (short)f2bf1(xa.w);
        af[4] = (short)f2bf1(xb.x); af[5] = (short)f2bf1(xb.y);
        af[6] = (short)f2bf1(xb.z); af[7] = (short)f2bf1(xb.w);
        #pragma unroll
        for (int t = 0; t < 8; ++t) {
            bf16x8 bfr = *(const bf16x8*)(Wt + (size_t)(t * 16 + m) * 128 + k0);
            acc[t] = __builtin_amdgcn_mfma_f32_16x16x32_bf16(af, bfr, acc[t], 0, 0, 0);
        }
    }
    #pragma unroll
    for (int t = 0; t < 8; ++t)
        #pragma unroll
        for (int r = 0; r < 4; ++r) {
            int rr = row0 + kg * 4 + r;
            if (rr < NN) Yb[(size_t)rr * 128 + t * 16 + m] = f2bf1(acc[t][r]);
        }
}

// ---------------- MFMA GEMM layer2: xwb[NN,64](bf16) = relu(BN1(agg1b)) @ W2 ----------------
// BN1 coefficients computed per-block in LDS from sums/ssq (bncoef fused).
__global__ __launch_bounds__(256) void mgemm2_k(const ushort* __restrict__ Xb,
                                                const ushort* __restrict__ Wt,
                                                const float* __restrict__ sums,
                                                const float* __restrict__ ssq,
                                                const float* __restrict__ g,
                                                const float* __restrict__ beta,
                                                ushort* __restrict__ Yb) {
    __shared__ float sc[128], shf[128];
    {
        int t = threadIdx.x;
        if (t < 128) {
            float m = sums[t] * (1.0f / NN);
            float var = ssq[t] * (1.0f / NN) - m * m;
            float s = g[t] * rsqrtf(var + BN_EPS);
            sc[t] = s;
            shf[t] = beta[t] - m * s;
        }
    }
    __syncthreads();
    const int lane = threadIdx.x & 63;
    const int wv = threadIdx.x >> 6;
    const int row0 = blockIdx.x * 64 + wv * 16;
    const int m = lane & 15;
    const int kg = lane >> 4;
    const int rowA = min(row0 + m, NN - 1);
    f32x4 acc[4];
    #pragma unroll
    for (int t = 0; t < 4; ++t) acc[t] = (f32x4){0.f, 0.f, 0.f, 0.f};

    #pragma unroll
    for (int kc = 0; kc < 128; kc += 32) {
        const int k0 = kc + kg * 8;
        uint4 raw = *(const uint4*)(Xb + (size_t)rowA * 128 + k0);
        float xs[8];
        xs[0] = bf_lo(raw.x); xs[1] = bf_hi(raw.x);
        xs[2] = bf_lo(raw.y); xs[3] = bf_hi(raw.y);
        xs[4] = bf_lo(raw.z); xs[5] = bf_hi(raw.z);
        xs[6] = bf_lo(raw.w); xs[7] = bf_hi(raw.w);
        float4 sa = *(const float4*)&sc[k0];
        float4 sb = *(const float4*)&sc[k0 + 4];
        float4 ha = *(const float4*)&shf[k0];
        float4 hb = *(const float4*)&shf[k0 + 4];
        xs[0] = fmaxf(fmaf(xs[0], sa.x, ha.x), 0.f);
        xs[1] = fmaxf(fmaf(xs[1], sa.y, ha.y), 0.f);
        xs[2] = fmaxf(fmaf(xs[2], sa.z, ha.z), 0.f);
        xs[3] = fmaxf(fmaf(xs[3], sa.w, ha.w), 0.f);
        xs[4] = fmaxf(fmaf(xs[4], sb.x, hb.x), 0.f);
        xs[5] = fmaxf(fmaf(xs[5], sb.y, hb.y), 0.f);
        xs[6] = fmaxf(fmaf(xs[6], sb.z, hb.z), 0.f);
        xs[7] = fmaxf(fmaf(xs[7], sb.w, hb.w), 0.f);
        bf16x8 af;
        #pragma unroll
        for (int i = 0; i < 8; ++i) af[i] = (short)f2bf1(xs[i]);
        #pragma unroll
        for (int t = 0; t < 4; ++t) {
            bf16x8 bfr = *(const bf16x8*)(Wt + (size_t)(t * 16 + m) * 128 + k0);
            acc[t] = __builtin_amdgcn_mfma_f32_16x16x32_bf16(af, bfr, acc[t], 0, 0, 0);
        }
    }
    #pragma unroll
    for (int t = 0; t < 4; ++t)
        #pragma unroll
        for (int r = 0; r < 4; ++r) {
            int rr = row0 + kg * 4 + r;
            if (rr < NN) Yb[(size_t)rr * 64 + t * 16 + m] = f2bf1(acc[t][r]);
        }
}

// ---------------- agg layer1 (D=128): one wave/node, 8-deep, bf16 in AND out (R7-proven) ----------------
__global__ __launch_bounds__(256) void agg128_k(const int* __restrict__ rowptr,
                                                const int* __restrict__ esrc,
                                                const float* __restrict__ ew,
                                                const float* __restrict__ dis,
                                                const uint32* __restrict__ xwb,
                                                const float* __restrict__ b,
                                                uint32* __restrict__ agg1b,
                                                float* __restrict__ sums,
                                                float* __restrict__ ssq) {
    const int lane = threadIdx.x & 63;
    const int wid = (blockIdx.x * 256 + threadIdx.x) >> 6;
    const int nwaves = gridDim.x * 4;
    float s0 = 0.f, s1 = 0.f, q0 = 0.f, q1 = 0.f;
    const float bc0 = b[lane * 2], bc1 = b[lane * 2 + 1];

    for (int n = wid; n < NN; n += nwaves) {
        const int beg = rowptr[n], end = rowptr[n + 1];
        const float dn = dis[n];
        float ax = 0.f, ay = 0.f;
        int e = beg;
        for (; e + 8 <= end; e += 8) {
            int idx[8]; float w[8]; uint32 vv[8];
            #pragma unroll
            for (int j = 0; j < 8; ++j) idx[j] = esrc[e + j];
            #pragma unroll
            for (int j = 0; j < 8; ++j) w[j] = ew[e + j];
            #pragma unroll
            for (int j = 0; j < 8; ++j)
                vv[j] = xwb[(size_t)idx[j] * 64 + lane];
            #pragma unroll
            for (int j = 0; j < 8; ++j) {
                ax = fmaf(bf_lo(vv[j]), w[j], ax);
                ay = fmaf(bf_hi(vv[j]), w[j], ay);
            }
        }
        for (; e < end; ++e) {
            int s = esrc[e];
            float w = ew[e];
            uint32 v = xwb[(size_t)s * 64 + lane];
            ax = fmaf(bf_lo(v), w, ax);
            ay = fmaf(bf_hi(v), w, ay);
        }
        float sl = dn * dn;  // self-loop norm 1/(deg+1)
        uint32 xv = xwb[(size_t)n * 64 + lane];
        ax = fmaf(bf_lo(xv), sl, ax) + bc0;
        ay = fmaf(bf_hi(xv), sl, ay) + bc1;
        agg1b[(size_t)n * 64 + lane] = f2bf_pair(ax, ay);
        s0 += ax; q0 = fmaf(ax, ax, q0);
        s1 += ay; q1 = fmaf(ay, ay, q1);
    }

    __shared__ float ls[256];
    ls[threadIdx.x] = 0.f;  // 256 = 2*D1
    __syncthreads();
    atomicAdd(&ls[lane * 2], s0);
    atomicAdd(&ls[lane * 2 + 1], s1);
    atomicAdd(&ls[128 + lane * 2], q0);
    atomicAdd(&ls[128 + lane * 2 + 1], q1);
    __syncthreads();
    if (threadIdx.x < 128) atomicAdd(&sums[threadIdx.x], ls[threadIdx.x]);
    else atomicAdd(&ssq[threadIdx.x - 128], ls[threadIdx.x]);
}

// ---------------- agg layer2 (D=64): half-wave per edge (R7-proven), bf16 output ----------------
__global__ __launch_bounds__(256) void agg64_k(const int* __restrict__ rowptr,
                                               const int* __restrict__ esrc,
                                               const float* __restrict__ ew,
                                               const float* __restrict__ dis,
                                               const uint32* __restrict__ xwb,  // 32 uint32/row
                                               const float* __restrict__ b,
                                               uint32* __restrict__ agg2b,
                                               float* __restrict__ sums,
                                               float* __restrict__ ssq) {
    const int lane = threadIdx.x & 63;
    const int half = lane >> 5;       // 0 or 1
    const int sl = lane & 31;         // covers cols {2sl, 2sl+1}
    const int wid = (blockIdx.x * 256 + threadIdx.x) >> 6;
    const int nwaves = gridDim.x * 4;
    float s0 = 0.f, s1 = 0.f, q0 = 0.f, q1 = 0.f;
    const float bc0 = b[sl * 2], bc1 = b[sl * 2 + 1];

    for (int n = wid; n < NN; n += nwaves) {
        const int beg = rowptr[n], end = rowptr[n + 1];
        const float dn = dis[n];
        float ax = 0.f, ay = 0.f;
        int e = beg;
        for (; e + 16 <= end; e += 16) {
            int idx[8]; float w[8]; uint32 vv[8];
            #pragma unroll
            for (int j = 0; j < 8; ++j) idx[j] = esrc[e + 2 * j + half];
            #pragma unroll
            for (int j = 0; j < 8; ++j) w[j] = ew[e + 2 * j + half];
            #pragma unroll
            for (int j = 0; j < 8; ++j)
                vv[j] = xwb[(size_t)idx[j] * 32 + sl];
            #pragma unroll
            for (int j = 0; j < 8; ++j) {
                ax = fmaf(bf_lo(vv[j]), w[j], ax);
                ay = fmaf(bf_hi(vv[j]), w[j], ay);
            }
        }
        for (; e + 2 <= end; e += 2) {
            int s = esrc[e + half];
            float w = ew[e + half];
            uint32 v = xwb[(size_t)s * 32 + sl];
            ax = fmaf(bf_lo(v), w, ax);
            ay = fmaf(bf_hi(v), w, ay);
        }
        if (e < end && half == 0) {
            int s = esrc[e];
            float w = ew[e];
            uint32 v = xwb[(size_t)s * 32 + sl];
            ax = fmaf(bf_lo(v), w, ax);
            ay = fmaf(bf_hi(v), w, ay);
        }
        ax += __shfl_down(ax, 32);
        ay += __shfl_down(ay, 32);
        if (half == 0) {
            float slf = dn * dn;
            uint32 xv = xwb[(size_t)n * 32 + sl];
            ax = fmaf(bf_lo(xv), slf, ax) + bc0;
            ay = fmaf(bf_hi(xv), slf, ay) + bc1;
            agg2b[(size_t)n * 32 + sl] = f2bf_pair(ax, ay);
            s0 += ax; q0 = fmaf(ax, ax, q0);
            s1 += ay; q1 = fmaf(ay, ay, q1);
        }
    }

    __shared__ float ls[128];  // 2*D2
    if (threadIdx.x < 128) ls[threadIdx.x] = 0.f;
    __syncthreads();
    if (half == 0) {
        atomicAdd(&ls[sl * 2], s0);
        atomicAdd(&ls[sl * 2 + 1], s1);
        atomicAdd(&ls[64 + sl * 2], q0);
        atomicAdd(&ls[64 + sl * 2 + 1], q1);
    }
    __syncthreads();
    if (threadIdx.x < 64) atomicAdd(&sums[threadIdx.x], ls[threadIdx.x]);
    else if (threadIdx.x < 128) atomicAdd(&ssq[threadIdx.x - 64], ls[threadIdx.x]);
}

// ---------------- final: out = relu(BN2(h2)) @ Wf + bf  (bncoef fused; 2 nodes/wave) ----------------
__global__ __launch_bounds__(256) void final_k(const uint32* __restrict__ h2b,
                                               const float* __restrict__ sums,
                                               const float* __restrict__ ssq,
                                               const float* __restrict__ g,
                                               const float* __restrict__ beta,
                                               const float* __restrict__ Wf,
                                               const float* __restrict__ bf,
                                               float* __restrict__ out) {
    __shared__ float sc[64], shf[64];
    {
        int t = threadIdx.x;
        if (t < 64) {
            float m = sums[t] * (1.0f / NN);
            float var = ssq[t] * (1.0f / NN) - m * m;
            float s = g[t] * rsqrtf(var + BN_EPS);
            sc[t] = s;
            shf[t] = beta[t] - m * s;
        }
    }
    __syncthreads();
    const int lane = threadIdx.x & 63;
    const int half = lane >> 5;
    const int sl = lane & 31;
    const int node = ((blockIdx.x * 256 + threadIdx.x) >> 6) * 2 + half;
    if (node >= NN) return;
    uint32 p = h2b[(size_t)node * 32 + sl];
    float2 wf = *(const float2*)&Wf[sl * 2];
    float v = fmaxf(fmaf(bf_lo(p), sc[sl * 2], shf[sl * 2]), 0.f) * wf.x;
    v = fmaf(fmaxf(fmaf(bf_hi(p), sc[sl * 2 + 1], shf[sl * 2 + 1]), 0.f), wf.y, v);
    #pragma unroll
    for (int o = 16; o > 0; o >>= 1) v += __shfl_down(v, o, 32);
    if (sl == 0) out[node] = v + bf[0];
}

extern "C" void kernel_launch(void* const* d_in, const int* in_sizes, int n_in,
                              void* d_out, int out_size, void* d_ws, size_t ws_size,
                              hipStream_t stream) {
    const float* x   = (const float*)d_in[0];
    const int*   ei  = (const int*)d_in[1];
    const int*   src = ei;
    const int*   dst = ei + NE;
    const float* W1  = (const float*)d_in[2];
    const float* b1  = (const float*)d_in[3];
    const float* g1  = (const float*)d_in[4];
    const float* be1 = (const float*)d_in[5];
    const float* W2  = (const float*)d_in[6];
    const float* b2  = (const float*)d_in[7];
    const float* g2  = (const float*)d_in[8];
    const float* be2 = (const float*)d_in[9];
    const float* Wf  = (const float*)d_in[10];
    const float* bf  = (const float*)d_in[11];
    float* out = (float*)d_out;

    // ---- workspace layout ----
    uint32* xwb   = (uint32*)d_ws;                     // NN*64 u32 (bf16 xw, both layers)
    uint32* agg1b = xwb + (size_t)NN * 64;             // NN*64 u32 (bf16 h1 pre-BN)
    uint32* agg2b = agg1b + (size_t)NN * 64;           // NN*32 u32 (bf16 h2 pre-BN)
    float*  dis   = (float*)(agg2b + (size_t)NN * 32); // NN
    ushort* wt1   = (ushort*)(dis + NN);               // 128*128 bf16
    ushort* wt2   = wt1 + 128 * 128;                   // 64*128 bf16
    int*    rowptr = (int*)(wt2 + 64 * 128);           // NN+1
    int*    bsum   = rowptr + NN + 1;                  // 256
    int*    esrc   = bsum + 256;                       // NE
    float*  ew     = (float*)(esrc + NE);              // NE
    // contiguous zero region: cnt | cur | sums1 | ssq1 | sums2 | ssq2
    int*    cnt    = (int*)(ew + NE);                  // NN
    int*    cur    = cnt + NN;                         // NN
    float*  sums1  = (float*)(cur + NN);               // 128
    float*  ssq1   = sums1 + D1;                       // 128
    float*  sums2  = ssq1 + D1;                        // 64
    float*  ssq2   = sums2 + D2;                       // 64

    hipMemsetAsync(cnt, 0, sizeof(int) * (2 * NN + 2 * D1 + 2 * D2), stream);

    // ---- CSR build + weight prep ----
    cnt_k<<<(NE + 255) / 256, 256, 0, stream>>>(dst, cnt);
    scan1_k<<<NB_SCAN, SCAN_CHUNK, 0, stream>>>(cnt, rowptr, bsum, dis);
    scan2_k<<<1, 64, 0, stream>>>(bsum);
    scan3_k<<<(NN + 255) / 256, 256, 0, stream>>>(rowptr, bsum);
    fill_k<<<(NE + 255) / 256, 256, 0, stream>>>(src, dst, rowptr, dis, cur, esrc, ew);
    wt_k<<<(128 * 128 + 64 * 128 + 255) / 256, 256, 0, stream>>>(W1, W2, wt1, wt2);

    // ---- layer 1 ----
    mgemm1_k<<<(NN + 63) / 64, 256, 0, stream>>>(x, wt1, (ushort*)xwb);
    agg128_k<<<2048, 256, 0, stream>>>(rowptr, esrc, ew, dis, xwb, b1, agg1b, sums1, ssq1);

    // ---- layer 2 (BN1 coef computed in-kernel from stats; BN1+ReLU fused into GEMM load) ----
    mgemm2_k<<<(NN + 63) / 64, 256, 0, stream>>>((const ushort*)agg1b, wt2, sums1, ssq1,
                                                 g1, be1, (ushort*)xwb);
    agg64_k<<<2048, 256, 0, stream>>>(rowptr, esrc, ew, dis, xwb, b2, agg2b, sums2, ssq2);

    // ---- final projection (BN2 coef computed in-kernel; BN2+ReLU fused) ----
    final_k<<<(NN / 2 + 3) / 4, 256, 0, stream>>>(agg2b, sums2, ssq2, g2, be2, Wf, bf, out);
}

// Round 11
// 466.315 us; speedup vs baseline: 1.7445x; 1.0137x over previous
//
#include <hip/hip_runtime.h>

#define NN 100000
#define NE 1600000
#define D1 128
#define D2 64
#define BN_EPS 1e-5f
#define SCAN_CHUNK 512
#define NB_SCAN ((NN + SCAN_CHUNK - 1) / SCAN_CHUNK)   // 196
#define NB_FILL (NE / 512)                              // 3125 (2 edges/thread)
#define NB_G1   ((NN + 63) / 64)                        // 1563

typedef unsigned int uint32;
typedef unsigned short ushort;
typedef __attribute__((ext_vector_type(8))) short bf16x8;
typedef __attribute__((ext_vector_type(4))) float f32x4;

// ---- bf16 helpers (RNE) ----
__device__ __forceinline__ ushort f2bf1(float f) {
    uint32 u = __float_as_uint(f);
    return (ushort)((u + 0x7FFFu + ((u >> 16) & 1u)) >> 16);
}
__device__ __forceinline__ uint32 f2bf_pair(float a, float b) {
    uint32 ua = __float_as_uint(a), ub = __float_as_uint(b);
    ua = (ua + 0x7FFFu + ((ua >> 16) & 1u)) >> 16;
    ub = (ub + 0x7FFFu + ((ub >> 16) & 1u)) >> 16;
    return ua | (ub << 16);
}
__device__ __forceinline__ float bf_lo(uint32 v) { return __uint_as_float(v << 16); }
__device__ __forceinline__ float bf_hi(uint32 v) { return __uint_as_float(v & 0xFFFF0000u); }

// ---------------- degree count (int atomics, from dst; 2 edges/thread) ----------------
__global__ __launch_bounds__(256) void cnt_k(const int* __restrict__ dst,
                                             int* __restrict__ cnt) {
    int i = blockIdx.x * 256 + threadIdx.x;
    int2 dd = *(const int2*)&dst[2 * i];
    atomicAdd(&cnt[dd.x], 1);
    atomicAdd(&cnt[dd.y], 1);
}

// ---------------- prefix scan part 1; also emits dis = rsqrt(cnt+1) ----------------
__global__ __launch_bounds__(SCAN_CHUNK) void scan1_k(const int* __restrict__ cnt,
                                                      int* __restrict__ rowptr,
                                                      int* __restrict__ bsum,
                                                      float* __restrict__ dis) {
    __shared__ int sh[SCAN_CHUNK];
    int tid = threadIdx.x;
    int g = blockIdx.x * SCAN_CHUNK + tid;
    int v = (g < NN) ? cnt[g] : 0;
    if (g < NN) dis[g] = rsqrtf((float)v + 1.0f);
    sh[tid] = v;
    __syncthreads();
    for (int o = 1; o < SCAN_CHUNK; o <<= 1) {
        int t = (tid >= o) ? sh[tid - o] : 0;
        __syncthreads();
        sh[tid] += t;
        __syncthreads();
    }
    if (g < NN) rowptr[g] = sh[tid] - v;
    if (tid == SCAN_CHUNK - 1) bsum[blockIdx.x] = sh[tid];
}

// ---------------- prefix scan part 2+3 fused: every block redoes the 196-wide bsum scan ----------------
__global__ __launch_bounds__(256) void scan23_k(int* __restrict__ rowptr,
                                                const int* __restrict__ bsum) {
    __shared__ int bs[256];
    int tid = threadIdx.x;
    bs[tid] = (tid < NB_SCAN) ? bsum[tid] : 0;
    __syncthreads();
    for (int o = 1; o < 256; o <<= 1) {
        int t = (tid >= o) ? bs[tid - o] : 0;
        __syncthreads();
        bs[tid] += t;
        __syncthreads();
    }
    int g = blockIdx.x * 256 + tid;
    if (g < NN) {
        int chunk = g >> 9;
        int add = (chunk == 0) ? 0 : bs[chunk - 1];
        rowptr[g] += add;
    }
    if (g == 0) rowptr[NN] = NE;
}

// ---------------- fused dispatch: CSR fill (blocks 0..NB_FILL) ∥ MFMA GEMM layer1 ----------------
// fill: 2 edges/thread, slot-atomic; writes esrc + ew.
// mgemm1: xwb[NN,128](bf16) = x[NN,128]f32 @ W1 (wt1 pre-transposed bf16).
__global__ __launch_bounds__(256) void fillgemm_k(const int* __restrict__ src,
                                                  const int* __restrict__ dst,
                                                  const int* __restrict__ rowptr,
                                                  const float* __restrict__ dis,
                                                  int* __restrict__ cur,
                                                  int* __restrict__ esrc,
                                                  float* __restrict__ ew,
                                                  const float* __restrict__ X,
                                                  const ushort* __restrict__ Wt,
                                                  ushort* __restrict__ Yb) {
    if (blockIdx.x < NB_FILL) {
        int i = blockIdx.x * 256 + threadIdx.x;
        int2 ss = *(const int2*)&src[2 * i];
        int2 dd = *(const int2*)&dst[2 * i];
        int p0 = rowptr[dd.x] + atomicAdd(&cur[dd.x], 1);
        esrc[p0] = ss.x;
        ew[p0] = dis[ss.x] * dis[dd.x];
        int p1 = rowptr[dd.y] + atomicAdd(&cur[dd.y], 1);
        esrc[p1] = ss.y;
        ew[p1] = dis[ss.y] * dis[dd.y];
        return;
    }
    // ---- mgemm1 body ----
    const int bid = blockIdx.x - NB_FILL;
    const int lane = threadIdx.x & 63;
    const int wv = threadIdx.x >> 6;
    const int row0 = bid * 64 + wv * 16;
    const int m = lane & 15;
    const int kg = lane >> 4;
    const int rowA = min(row0 + m, NN - 1);
    f32x4 acc[8];
    #pragma unroll
    for (int t = 0; t < 8; ++t) acc[t] = (f32x4){0.f, 0.f, 0.f, 0.f};

    #pragma unroll
    for (int kc = 0; kc < 128; kc += 32) {
        const int k0 = kc + kg * 8;
        float4 xa = *(const float4*)(X + (size_t)rowA * 128 + k0);
        float4 xb = *(const float4*)(X + (size_t)rowA * 128 + k0 + 4);
        bf16x8 af;
        af[0] = (short)f2bf1(xa.x); af[1] = (short)f2bf1(xa.y);
        af[2] = (short)f2bf1(xa.z); af[3] = (short)f2bf1(xa.w);
        af[4] = (short)f2bf1(xb.x); af[5] = (short)f2bf1(xb.y);
        af[6] = (short)f2bf1(xb.z); af[7] = (short)f2bf1(xb.w);
        #pragma unroll
        for (int t = 0; t < 8; ++t) {
            bf16x8 bfr = *(const bf16x8*)(Wt + (size_t)(t * 16 + m) * 128 + k0);
            acc[t] = __builtin_amdgcn_mfma_f32_16x16x32_bf16(af, bfr, acc[t], 0, 0, 0);
        }
    }
    #pragma unroll
    for (int t = 0; t < 8; ++t)
        #pragma unroll
        for (int r = 0; r < 4; ++r) {
            int rr = row0 + kg * 4 + r;
            if (rr < NN) Yb[(size_t)rr * 128 + t * 16 + m] = f2bf1(acc[t][r]);
        }
}

// ---------------- W transpose + bf16 convert: Wt[c][k] = bf16(W[k][c]) ----------------
__global__ __launch_bounds__(256) void wt_k(const float* __restrict__ W1,
                                            const float* __restrict__ W2,
                                            ushort* __restrict__ wt1,
                                            ushort* __restrict__ wt2) {
    int i = blockIdx.x * 256 + threadIdx.x;
    if (i < 128 * 128) {
        int c = i >> 7, k = i & 127;
        wt1[i] = f2bf1(W1[k * 128 + c]);
    } else if (i < 128 * 128 + 64 * 128) {
        int o = i - 128 * 128;
        int c = o >> 7, k = o & 127;
        wt2[o] = f2bf1(W2[k * 64 + c]);
    }
}

// ---------------- MFMA GEMM layer2: xwb[NN,64](bf16) = relu(BN1(agg1b)) @ W2 (frozen R10) ----------------
__global__ __launch_bounds__(256) void mgemm2_k(const ushort* __restrict__ Xb,
                                                const ushort* __restrict__ Wt,
                                                const float* __restrict__ sums,
                                                const float* __restrict__ ssq,
                                                const float* __restrict__ g,
                                                const float* __restrict__ beta,
                                                ushort* __restrict__ Yb) {
    __shared__ float sc[128], shf[128];
    {
        int t = threadIdx.x;
        if (t < 128) {
            float m = sums[t] * (1.0f / NN);
            float var = ssq[t] * (1.0f / NN) - m * m;
            float s = g[t] * rsqrtf(var + BN_EPS);
            sc[t] = s;
            shf[t] = beta[t] - m * s;
        }
    }
    __syncthreads();
    const int lane = threadIdx.x & 63;
    const int wv = threadIdx.x >> 6;
    const int row0 = blockIdx.x * 64 + wv * 16;
    const int m = lane & 15;
    const int kg = lane >> 4;
    const int rowA = min(row0 + m, NN - 1);
    f32x4 acc[4];
    #pragma unroll
    for (int t = 0; t < 4; ++t) acc[t] = (f32x4){0.f, 0.f, 0.f, 0.f};

    #pragma unroll
    for (int kc = 0; kc < 128; kc += 32) {
        const int k0 = kc + kg * 8;
        uint4 raw = *(const uint4*)(Xb + (size_t)rowA * 128 + k0);
        float xs[8];
        xs[0] = bf_lo(raw.x); xs[1] = bf_hi(raw.x);
        xs[2] = bf_lo(raw.y); xs[3] = bf_hi(raw.y);
        xs[4] = bf_lo(raw.z); xs[5] = bf_hi(raw.z);
        xs[6] = bf_lo(raw.w); xs[7] = bf_hi(raw.w);
        float4 sa = *(const float4*)&sc[k0];
        float4 sb = *(const float4*)&sc[k0 + 4];
        float4 ha = *(const float4*)&shf[k0];
        float4 hb = *(const float4*)&shf[k0 + 4];
        xs[0] = fmaxf(fmaf(xs[0], sa.x, ha.x), 0.f);
        xs[1] = fmaxf(fmaf(xs[1], sa.y, ha.y), 0.f);
        xs[2] = fmaxf(fmaf(xs[2], sa.z, ha.z), 0.f);
        xs[3] = fmaxf(fmaf(xs[3], sa.w, ha.w), 0.f);
        xs[4] = fmaxf(fmaf(xs[4], sb.x, hb.x), 0.f);
        xs[5] = fmaxf(fmaf(xs[5], sb.y, hb.y), 0.f);
        xs[6] = fmaxf(fmaf(xs[6], sb.z, hb.z), 0.f);
        xs[7] = fmaxf(fmaf(xs[7], sb.w, hb.w), 0.f);
        bf16x8 af;
        #pragma unroll
        for (int i = 0; i < 8; ++i) af[i] = (short)f2bf1(xs[i]);
        #pragma unroll
        for (int t = 0; t < 4; ++t) {
            bf16x8 bfr = *(const bf16x8*)(Wt + (size_t)(t * 16 + m) * 128 + k0);
            acc[t] = __builtin_amdgcn_mfma_f32_16x16x32_bf16(af, bfr, acc[t], 0, 0, 0);
        }
    }
    #pragma unroll
    for (int t = 0; t < 4; ++t)
        #pragma unroll
        for (int r = 0; r < 4; ++r) {
            int rr = row0 + kg * 4 + r;
            if (rr < NN) Yb[(size_t)rr * 64 + t * 16 + m] = f2bf1(acc[t][r]);
        }
}

// ---------------- agg layer1 (D=128): frozen R10 ----------------
__global__ __launch_bounds__(256) void agg128_k(const int* __restrict__ rowptr,
                                                const int* __restrict__ esrc,
                                                const float* __restrict__ ew,
                                                const float* __restrict__ dis,
                                                const uint32* __restrict__ xwb,
                                                const float* __restrict__ b,
                                                uint32* __restrict__ agg1b,
                                                float* __restrict__ sums,
                                                float* __restrict__ ssq) {
    const int lane = threadIdx.x & 63;
    const int wid = (blockIdx.x * 256 + threadIdx.x) >> 6;
    const int nwaves = gridDim.x * 4;
    float s0 = 0.f, s1 = 0.f, q0 = 0.f, q1 = 0.f;
    const float bc0 = b[lane * 2], bc1 = b[lane * 2 + 1];

    for (int n = wid; n < NN; n += nwaves) {
        const int beg = rowptr[n], end = rowptr[n + 1];
        const float dn = dis[n];
        float ax = 0.f, ay = 0.f;
        int e = beg;
        for (; e + 8 <= end; e += 8) {
            int idx[8]; float w[8]; uint32 vv[8];
            #pragma unroll
            for (int j = 0; j < 8; ++j) idx[j] = esrc[e + j];
            #pragma unroll
            for (int j = 0; j < 8; ++j) w[j] = ew[e + j];
            #pragma unroll
            for (int j = 0; j < 8; ++j)
                vv[j] = xwb[(size_t)idx[j] * 64 + lane];
            #pragma unroll
            for (int j = 0; j < 8; ++j) {
                ax = fmaf(bf_lo(vv[j]), w[j], ax);
                ay = fmaf(bf_hi(vv[j]), w[j], ay);
            }
        }
        for (; e < end; ++e) {
            int s = esrc[e];
            float w = ew[e];
            uint32 v = xwb[(size_t)s * 64 + lane];
            ax = fmaf(bf_lo(v), w, ax);
            ay = fmaf(bf_hi(v), w, ay);
        }
        float sl = dn * dn;  // self-loop norm 1/(deg+1)
        uint32 xv = xwb[(size_t)n * 64 + lane];
        ax = fmaf(bf_lo(xv), sl, ax) + bc0;
        ay = fmaf(bf_hi(xv), sl, ay) + bc1;
        agg1b[(size_t)n * 64 + lane] = f2bf_pair(ax, ay);
        s0 += ax; q0 = fmaf(ax, ax, q0);
        s1 += ay; q1 = fmaf(ay, ay, q1);
    }

    __shared__ float ls[256];
    ls[threadIdx.x] = 0.f;
    __syncthreads();
    atomicAdd(&ls[lane * 2], s0);
    atomicAdd(&ls[lane * 2 + 1], s1);
    atomicAdd(&ls[128 + lane * 2], q0);
    atomicAdd(&ls[128 + lane * 2 + 1], q1);
    __syncthreads();
    if (threadIdx.x < 128) atomicAdd(&sums[threadIdx.x], ls[threadIdx.x]);
    else atomicAdd(&ssq[threadIdx.x - 128], ls[threadIdx.x]);
}

// ---------------- agg layer2 (D=64): frozen R10 ----------------
__global__ __launch_bounds__(256) void agg64_k(const int* __restrict__ rowptr,
                                               const int* __restrict__ esrc,
                                               const float* __restrict__ ew,
                                               const float* __restrict__ dis,
                                               const uint32* __restrict__ xwb,  // 32 uint32/row
                                               const float* __restrict__ b,
                                               uint32* __restrict__ agg2b,
                                               float* __restrict__ sums,
                                               float* __restrict__ ssq) {
    const int lane = threadIdx.x & 63;
    const int half = lane >> 5;
    const int sl = lane & 31;
    const int wid = (blockIdx.x * 256 + threadIdx.x) >> 6;
    const int nwaves = gridDim.x * 4;
    float s0 = 0.f, s1 = 0.f, q0 = 0.f, q1 = 0.f;
    const float bc0 = b[sl * 2], bc1 = b[sl * 2 + 1];

    for (int n = wid; n < NN; n += nwaves) {
        const int beg = rowptr[n], end = rowptr[n + 1];
        const float dn = dis[n];
        float ax = 0.f, ay = 0.f;
        int e = beg;
        for (; e + 16 <= end; e += 16) {
            int idx[8]; float w[8]; uint32 vv[8];
            #pragma unroll
            for (int j = 0; j < 8; ++j) idx[j] = esrc[e + 2 * j + half];
            #pragma unroll
            for (int j = 0; j < 8; ++j) w[j] = ew[e + 2 * j + half];
            #pragma unroll
            for (int j = 0; j < 8; ++j)
                vv[j] = xwb[(size_t)idx[j] * 32 + sl];
            #pragma unroll
            for (int j = 0; j < 8; ++j) {
                ax = fmaf(bf_lo(vv[j]), w[j], ax);
                ay = fmaf(bf_hi(vv[j]), w[j], ay);
            }
        }
        for (; e + 2 <= end; e += 2) {
            int s = esrc[e + half];
            float w = ew[e + half];
            uint32 v = xwb[(size_t)s * 32 + sl];
            ax = fmaf(bf_lo(v), w, ax);
            ay = fmaf(bf_hi(v), w, ay);
        }
        if (e < end && half == 0) {
            int s = esrc[e];
            float w = ew[e];
            uint32 v = xwb[(size_t)s * 32 + sl];
            ax = fmaf(bf_lo(v), w, ax);
            ay = fmaf(bf_hi(v), w, ay);
        }
        ax += __shfl_down(ax, 32);
        ay += __shfl_down(ay, 32);
        if (half == 0) {
            float slf = dn * dn;
            uint32 xv = xwb[(size_t)n * 32 + sl];
            ax = fmaf(bf_lo(xv), slf, ax) + bc0;
            ay = fmaf(bf_hi(xv), slf, ay) + bc1;
            agg2b[(size_t)n * 32 + sl] = f2bf_pair(ax, ay);
            s0 += ax; q0 = fmaf(ax, ax, q0);
            s1 += ay; q1 = fmaf(ay, ay, q1);
        }
    }

    __shared__ float ls[128];
    if (threadIdx.x < 128) ls[threadIdx.x] = 0.f;
    __syncthreads();
    if (half == 0) {
        atomicAdd(&ls[sl * 2], s0);
        atomicAdd(&ls[sl * 2 + 1], s1);
        atomicAdd(&ls[64 + sl * 2], q0);
        atomicAdd(&ls[64 + sl * 2 + 1], q1);
    }
    __syncthreads();
    if (threadIdx.x < 64) atomicAdd(&sums[threadIdx.x], ls[threadIdx.x]);
    else if (threadIdx.x < 128) atomicAdd(&ssq[threadIdx.x - 64], ls[threadIdx.x]);
}

// ---------------- final: frozen R10 ----------------
__global__ __launch_bounds__(256) void final_k(const uint32* __restrict__ h2b,
                                               const float* __restrict__ sums,
                                               const float* __restrict__ ssq,
                                               const float* __restrict__ g,
                                               const float* __restrict__ beta,
                                               const float* __restrict__ Wf,
                                               const float* __restrict__ bf,
                                               float* __restrict__ out) {
    __shared__ float sc[64], shf[64];
    {
        int t = threadIdx.x;
        if (t < 64) {
            float m = sums[t] * (1.0f / NN);
            float var = ssq[t] * (1.0f / NN) - m * m;
            float s = g[t] * rsqrtf(var + BN_EPS);
            sc[t] = s;
            shf[t] = beta[t] - m * s;
        }
    }
    __syncthreads();
    const int lane = threadIdx.x & 63;
    const int half = lane >> 5;
    const int sl = lane & 31;
    const int node = ((blockIdx.x * 256 + threadIdx.x) >> 6) * 2 + half;
    if (node >= NN) return;
    uint32 p = h2b[(size_t)node * 32 + sl];
    float2 wf = *(const float2*)&Wf[sl * 2];
    float v = fmaxf(fmaf(bf_lo(p), sc[sl * 2], shf[sl * 2]), 0.f) * wf.x;
    v = fmaf(fmaxf(fmaf(bf_hi(p), sc[sl * 2 + 1], shf[sl * 2 + 1]), 0.f), wf.y, v);
    #pragma unroll
    for (int o = 16; o > 0; o >>= 1) v += __shfl_down(v, o, 32);
    if (sl == 0) out[node] = v + bf[0];
}

extern "C" void kernel_launch(void* const* d_in, const int* in_sizes, int n_in,
                              void* d_out, int out_size, void* d_ws, size_t ws_size,
                              hipStream_t stream) {
    const float* x   = (const float*)d_in[0];
    const int*   ei  = (const int*)d_in[1];
    const int*   src = ei;
    const int*   dst = ei + NE;
    const float* W1  = (const float*)d_in[2];
    const float* b1  = (const float*)d_in[3];
    const float* g1  = (const float*)d_in[4];
    const float* be1 = (const float*)d_in[5];
    const float* W2  = (const float*)d_in[6];
    const float* b2  = (const float*)d_in[7];
    const float* g2  = (const float*)d_in[8];
    const float* be2 = (const float*)d_in[9];
    const float* Wf  = (const float*)d_in[10];
    const float* bf  = (const float*)d_in[11];
    float* out = (float*)d_out;

    // ---- workspace layout (identical to R10) ----
    uint32* xwb   = (uint32*)d_ws;                     // NN*64 u32 (bf16 xw, both layers)
    uint32* agg1b = xwb + (size_t)NN * 64;             // NN*64 u32 (bf16 h1 pre-BN)
    uint32* agg2b = agg1b + (size_t)NN * 64;           // NN*32 u32 (bf16 h2 pre-BN)
    float*  dis   = (float*)(agg2b + (size_t)NN * 32); // NN
    ushort* wt1   = (ushort*)(dis + NN);               // 128*128 bf16
    ushort* wt2   = wt1 + 128 * 128;                   // 64*128 bf16
    int*    rowptr = (int*)(wt2 + 64 * 128);           // NN+1
    int*    bsum   = rowptr + NN + 1;                  // 256
    int*    esrc   = bsum + 256;                       // NE
    float*  ew     = (float*)(esrc + NE);              // NE
    int*    cnt    = (int*)(ew + NE);                  // NN
    int*    cur    = cnt + NN;                         // NN
    float*  sums1  = (float*)(cur + NN);               // 128
    float*  ssq1   = sums1 + D1;                       // 128
    float*  sums2  = ssq1 + D1;                        // 64
    float*  ssq2   = sums2 + D2;                       // 64

    hipMemsetAsync(cnt, 0, sizeof(int) * (2 * NN + 2 * D1 + 2 * D2), stream);

    // ---- weight prep + CSR build ----
    wt_k<<<(128 * 128 + 64 * 128 + 255) / 256, 256, 0, stream>>>(W1, W2, wt1, wt2);
    cnt_k<<<NE / 512, 256, 0, stream>>>(dst, cnt);
    scan1_k<<<NB_SCAN, SCAN_CHUNK, 0, stream>>>(cnt, rowptr, bsum, dis);
    scan23_k<<<(NN + 255) / 256, 256, 0, stream>>>(rowptr, bsum);

    // ---- fill ∥ layer-1 GEMM (independent; co-scheduled in one dispatch) ----
    fillgemm_k<<<NB_FILL + NB_G1, 256, 0, stream>>>(src, dst, rowptr, dis, cur, esrc, ew,
                                                    x, wt1, (ushort*)xwb);

    // ---- layer 1 aggregate ----
    agg128_k<<<2048, 256, 0, stream>>>(rowptr, esrc, ew, dis, xwb, b1, agg1b, sums1, ssq1);

    // ---- layer 2 ----
    mgemm2_k<<<(NN + 63) / 64, 256, 0, stream>>>((const ushort*)agg1b, wt2, sums1, ssq1,
                                                 g1, be1, (ushort*)xwb);
    agg64_k<<<2048, 256, 0, stream>>>(rowptr, esrc, ew, dis, xwb, b2, agg2b, sums2, ssq2);

    // ---- final projection ----
    final_k<<<(NN / 2 + 3) / 4, 256, 0, stream>>>(agg2b, sums2, ssq2, g2, be2, Wf, bf, out);
}